// Round 4
// baseline (389.746 us; speedup 1.0000x reference)
//
#include <hip/hip_runtime.h>
#include <stdint.h>

// ---------------------------------------------------------------------------
// StochasticKeyNet — R13: mega-kernel, hierarchical L2-point barrier arrival.
// R12 post-mortem: occupancy doubled (47%) but dur 243->257us; phases are NOT
// wave-latency-bound.  Bottom-up: work ~55us, leaving ~16us/barrier.  Culprit:
// 128 AGENT-scope RMWs per XCD on ONE leaf line = IF-point serialized
// (~400cyc each ~ 21us).  R13: census slot at entry; per barrier blocks RMW
// per-(XCD, slot/8) mid counters at WORKGROUP scope (L2-point, 8-deep), mid-
// last bumps XCD leaf (<=16-deep L2-point), leaf-last does the proven R11/R12
// release(wbl2)/root(IF)/acquire(inv) sequence.  Est 2-3us/barrier.
// Also: fc1 split-K (2 half-K waves + 512B LDS reduce).
// Work decomposition, conv math, layouts identical to R12.
// ---------------------------------------------------------------------------

#define B 128
#define ZPAD 2048   // leading zero page (elements) in each packed act buffer
#define NBLK 1024
#define NTHR 256
#define JSTRIDE ((NBLK >> 3) * 4)   // 512 wave-slots per work partition
#define AGT __HIP_MEMORY_SCOPE_AGENT
#define WGS __HIP_MEMORY_SCOPE_WORKGROUP

typedef _Float16 f16_t;
typedef __attribute__((ext_vector_type(8))) _Float16 f16x8;
typedef __attribute__((ext_vector_type(4))) _Float16 f16x4;
typedef __attribute__((ext_vector_type(4))) float f32x4;

struct WArgs {
    const float* w[9]; const float* b[9];
    int Ci[9], Co[9], KS[9], Cp[9], NCG[9];
    int woff[10]; int boff[10];
};

// ---------------- physical XCD id (learn_hip m09: returns 0..7) -------------
__device__ __forceinline__ int xcc_id() {
    int x;
    asm("s_getreg_b32 %0, hwreg(20, 0, 32)" : "=s"(x));   // HW_REG_XCC_ID
    return x & 7;
}

// ---------------- grid barrier --------------------------------------------
// bar layout (ints, 32-int = 128B line stride):
//   mid(x,m)  = (x*16+m)*32     [0..4095]   WG-scope RMW (local-TCC point)
//   leaf(x)   = 4096 + x*32                 WG-scope RMW (local-TCC point)
//   ldone(x)  = 4352 + x*32                 AGENT store/poll (IF point)
//   root      = 4608                        AGENT RMW/poll (IF point)
//   cnt(x)    = 4640 + x                    census (AGENT)
// All zeroed per launch by hipMemsetAsync; memset kernel's end-of-kernel
// release + our dispatch entry-acquire make the zeros visible everywhere.
__device__ __forceinline__ void gbar(int* bar, int ph, int slot) {
    __syncthreads();                               // drains vmcnt: stores in L2
    if (threadIdx.x == 0) {
        const int x = xcc_id();
        int* root = bar + 4608;
        int* cnt  = bar + 4640;
        if (ph == 0) {                             // census settle (entry RMWs)
            for (;;) {
                int s = 0;
#pragma unroll
                for (int k = 0; k < 8; ++k)
                    s += __hip_atomic_load(cnt + k, __ATOMIC_RELAXED, AGT);
                if (s == NBLK) break;
                __builtin_amdgcn_s_sleep(2);
            }
        }
        const int myc = __hip_atomic_load(cnt + x, __ATOMIC_RELAXED, AGT);
        int nact = 0;
#pragma unroll
        for (int k = 0; k < 8; ++k)
            nact += (__hip_atomic_load(cnt + k, __ATOMIC_RELAXED, AGT) != 0) ? 1 : 0;
        const int m  = slot >> 3;                  // my mid group (<=16 per XCD)
        const int mc = min(8, myc - m * 8);        // members of my mid group
        const int nm = (myc + 7) >> 3;             // mid groups on this XCD
        int* mid   = bar + (x * 16 + m) * 32;
        int* leaf  = bar + 4096 + x * 32;
        int* ldone = bar + 4352 + x * 32;
        bool last = false;
        // L2-point arrival (same-XCD participants only -> local TCC coherent)
        int mo = __hip_atomic_fetch_add(mid, 1, __ATOMIC_RELAXED, WGS);
        if (mo == (ph + 1) * mc - 1) {
            int lo = __hip_atomic_fetch_add(leaf, 1, __ATOMIC_RELAXED, WGS);
            last = (lo == (ph + 1) * nm - 1);
        }
        if (last) {
            // all local blocks' stores are in this L2 (their syncthreads
            // drained vmcnt before their mid RMW) -> one wbl2 publishes all.
            __builtin_amdgcn_fence(__ATOMIC_RELEASE, "agent");   // wbl2 sc1
            __hip_atomic_fetch_add(root, 1, __ATOMIC_RELAXED, AGT);
            while (__hip_atomic_load(root, __ATOMIC_RELAXED, AGT) < (ph + 1) * nact)
                __builtin_amdgcn_s_sleep(8);
            __builtin_amdgcn_fence(__ATOMIC_ACQUIRE, "agent");   // inv L1+L2
            __hip_atomic_store(ldone, ph + 1, __ATOMIC_RELAXED, AGT);
        } else {
            while (__hip_atomic_load(ldone, __ATOMIC_RELAXED, AGT) < ph + 1)
                __builtin_amdgcn_s_sleep(8);
            // XCD L2 already invalidated by designated block; local L1 only.
            asm volatile("buffer_inv sc0\n\ts_waitcnt vmcnt(0)" ::: "memory");
        }
    }
    __syncthreads();
}

// ---------------- phase 0: weight pack + zero-init + decode+pack ------------
__device__ void prep_phase(const WArgs& A,
                           const float* __restrict__ x0, const int* __restrict__ perm0,
                           const float* __restrict__ diag0,
                           f16_t* __restrict__ wp, float* __restrict__ bp,
                           f16_t* __restrict__ x8a, f16_t* __restrict__ x8b,
                           float* __restrict__ t0) {
    const int NT = NBLK * NTHR;
    const int gtid = blockIdx.x * NTHR + threadIdx.x;
    // zero pages of both act buffers (conv stores never write below ZPAD)
    for (int idx = gtid; idx < ZPAD; idx += NT) {
        x8a[idx] = (f16_t)0.f; x8b[idx] = (f16_t)0.f;
    }
    // zero ci%8 slots 3..7 of the l0 input region of x8a (byte-disjoint from
    // decode's slots 0..2)
    for (int idx = gtid; idx < 1024 * 128; idx += NT) {
        int p = idx >> 7, n = idx & 127;
        f16_t* base = x8a + ZPAD + p * 1024 + n * 8;
        base[3] = (f16_t)0.f;
        *(uint64_t*)(base + 4) = 0ull;
    }
    // bias pack
    for (int idx = gtid; idx < A.boff[9]; idx += NT) {
        int l = 0;
        while (idx >= A.boff[l + 1]) ++l;
        int co = idx - A.boff[l];
        bp[idx] = (co < A.Co[l]) ? A.b[l][co] : 0.f;
    }
    // weight pack to f16 [chunk][4][Cp][8]
    for (int idx = gtid; idx < A.woff[9]; idx += NT) {
        int l = 0;
        while (idx >= A.woff[l + 1]) ++l;
        int e = idx - A.woff[l];
        int j = e & 7;
        int t1_ = e >> 3;
        int Cp = A.Cp[l];
        int co = t1_ % Cp;
        int gg = t1_ / Cp;
        int ncg = A.NCG[l];
        int tap = gg / ncg, cg = gg - tap * ncg;
        int ks = A.KS[l];
        int kh = tap / ks, kw = tap - kh * ks;
        int ci = cg * 8 + j;
        float val = 0.f;
        if (co < A.Co[l] && tap < ks * ks && ci < A.Ci[l])
            val = A.w[l][(((size_t)co * A.Ci[l] + ci) * ks + kh) * ks + kw];
        wp[idx] = (f16_t)val;
    }
    // fused decode + f16 pack: v[perm[j]] = x[j]/diag[j]
    for (int idx = gtid; idx < 3073 * B; idx += NT) {
        int row = idx >> 7, n = idx & 127;
        int i = perm0[row];
        float val = x0[(size_t)row * B + n] / diag0[row];
        if (i < 3072) {
            int c = i >> 10, pp = i & 1023;
            x8a[ZPAD + pp * 1024 + n * 8 + c] = (f16_t)val;
        } else {
            t0[n] = val;
        }
    }
}

// ---------------- one conv layer (wave-granular persistent units) -----------
// Unit j: nh (batch split) -> cog (co group) -> pixel; partition X=blockIdx&7.
template <int KS, int NS, int NSPLIT, int CB, bool F32OUT,
          int Hi, int Wo_log2, int HWo, int STRD, int PAD,
          int NCG, int NCHUNK, int KGR, int Co, int Cp>
__device__ __forceinline__ void conv_layer(
    const f16_t* __restrict__ xin, const float* __restrict__ t_in,
    const f16_t* __restrict__ wp, const float* __restrict__ bp,
    f16_t* __restrict__ xout, float* __restrict__ t_out, float* __restrict__ f32out)
{
    constexpr int PF = 2;
    constexpr int MS = 4;
    constexpr int Wi = Hi;
    constexpr int PB8 = HWo / 8;
    constexpr int UJ = NSPLIT * CB * PB8;
    constexpr int HiWi = Hi * Wi;
    constexpr int HiWi4 = 4 * HiWi;
    constexpr int NCGHW = NCG * HiWi;
    const int wv = threadIdx.x >> 6;               // 0..3
    const int lane = threadIdx.x & 63;
    const int q = lane >> 4;
    const int r = lane & 15;
    const int X = blockIdx.x & 7;

    // t-row relu (once per layer, block 0)
    if (blockIdx.x == 0 && threadIdx.x < B) {
        float tvv = fmaxf(t_in[threadIdx.x], 0.f);
        if (F32OUT) f32out[(size_t)Co * HWo * B + threadIdx.x] = tvv;
        else        t_out[threadIdx.x] = tvv;
    }

    for (int j = (blockIdx.x >> 3) * 4 + wv; j < UJ; j += JSTRIDE) {
        int nh = 0, j2 = j;
        if (NSPLIT > 1) { nh = j % NSPLIT; j2 = j / NSPLIT; }
        const int cog = (CB > 1) ? (j2 % CB) : 0;
        const int jp  = (CB > 1) ? (j2 / CB) : j2;
        const int p = X * PB8 + jp;
        const int co0 = cog * 64;
        const int ncol0 = nh * (NS * 16);
        const int ncol8 = ncol0 * 8;
        const int ho = p >> Wo_log2;
        const int wo = p & ((1 << Wo_log2) - 1);
        const f16_t* xdata = xin + ZPAD;

        float tv[NS];
#pragma unroll
        for (int ns = 0; ns < NS; ++ns) tv[ns] = t_in[ncol0 + ns * 16 + r];

        f32x4 acc[MS][NS];
#pragma unroll
        for (int ms = 0; ms < MS; ++ms) {
            float4 b4 = *(const float4*)(bp + co0 + ms * 16 + q * 4);
#pragma unroll
            for (int ns = 0; ns < NS; ++ns) {
                acc[ms][ns][0] = b4.x * tv[ns];
                acc[ms][ns][1] = b4.y * tv[ns];
                acc[ms][ns][2] = b4.z * tv[ns];
                acc[ms][ns][3] = b4.w * tv[ns];
            }
        }

        const int hb = ho * STRD - PAD, wb = wo * STRD - PAD;
        const int wend = wb + KS;

        int g = q, cg = q, hi = hb, wi = wb, cgHW;
        {
            while (cg >= NCG) { cg -= NCG; ++wi; if (wi == wend) { wi = wb; ++hi; } }
            cgHW = cg * HiWi;
        }

        f16x8 bf[PF][NS], af[PF][MS];

        auto advance = [&]() {
            g += 4; cg += 4; cgHW += HiWi4;
            if constexpr (NCG >= 4) {            // at most one wrap
                int c2 = cg - NCG;
                bool wrap = c2 >= 0;
                int wn = wi + 1;
                bool ww = wrap & (wn == wend);
                cg   = wrap ? c2 : cg;
                cgHW = wrap ? cgHW - NCGHW : cgHW;
                wi   = wrap ? (ww ? wb : wn) : wi;
                hi   = ww ? hi + 1 : hi;
            } else {
                while (cg >= NCG) { cg -= NCG; cgHW -= NCGHW; ++wi; if (wi == wend) { wi = wb; ++hi; } }
            }
        };
        auto loadB = [&](f16x8* bb8) {
            bool v = (g < KGR) & ((unsigned)hi < (unsigned)Hi) & ((unsigned)wi < (unsigned)Wi);
            int boff = (cgHW + hi * Wi + wi) << 10;        // *128*8 elements
            const f16_t* bb = xdata + (v ? boff : -ZPAD) + ncol8 + r * 8;
#pragma unroll
            for (int ns = 0; ns < NS; ++ns) bb8[ns] = *(const f16x8*)(bb + ns * 128);
        };
        auto loadA = [&](f16x8* a, int c) {
            int ac = c < NCHUNK ? c : NCHUNK - 1;          // clamp phantom chunks
            const f16_t* ap = wp + (((ac * 4 + q) * Cp) + co0 + r) * 8;
#pragma unroll
            for (int ms = 0; ms < MS; ++ms) a[ms] = *(const f16x8*)(ap + ms * 128);
        };
        auto domfma = [&](f16x8* a, f16x8* bb8) {
#pragma unroll
            for (int ms = 0; ms < MS; ++ms)
#pragma unroll
                for (int ns = 0; ns < NS; ++ns)
                    acc[ms][ns] = __builtin_amdgcn_mfma_f32_16x16x32_f16(a[ms], bb8[ns], acc[ms][ns], 0, 0, 0);
        };

#pragma unroll
        for (int pf = 0; pf < PF; ++pf) { loadB(bf[pf]); loadA(af[pf], pf); advance(); }
        constexpr int nck = ((NCHUNK + PF - 1) / PF) * PF;
        for (int c = 0; c < nck; c += PF) {
#pragma unroll
            for (int pf = 0; pf < PF; ++pf) {
                domfma(af[pf], bf[pf]);
                loadB(bf[pf]); loadA(af[pf], c + PF + pf); advance();
            }
        }

        if constexpr (!F32OUT) {
#pragma unroll
            for (int ms = 0; ms < MS; ++ms) {
                int cob = co0 + ms * 16 + q * 4;
                if (cob < Co) {
                    int off0 = ((cob >> 3) * HWo + p) * 1024 + (cob & 7) + ncol8 + r * 8;
#pragma unroll
                    for (int ns = 0; ns < NS; ++ns) {
                        f16x4 h;
                        h[0] = (f16_t)fmaxf(acc[ms][ns][0], 0.f);
                        h[1] = (f16_t)fmaxf(acc[ms][ns][1], 0.f);
                        h[2] = (f16_t)fmaxf(acc[ms][ns][2], 0.f);
                        h[3] = (f16_t)fmaxf(acc[ms][ns][3], 0.f);
                        *(f16x4*)(xout + ZPAD + off0 + ns * 128) = h;
                    }
                }
            }
        } else {
#pragma unroll
            for (int ms = 0; ms < MS; ++ms)
#pragma unroll
                for (int ns = 0; ns < NS; ++ns)
#pragma unroll
                    for (int e = 0; e < 4; ++e) {
                        int co = co0 + ms * 16 + q * 4 + e;
                        if (co < Co)
                            f32out[((size_t)co * HWo + p) * B + ncol0 + ns * 16 + r] =
                                fmaxf(acc[ms][ns][e], 0.f);
                    }
        }
    }
}

// ---------------- FC phases -------------------------------------------------
// fc1: split-K across the two 128-thread halves, 512B LDS reduce.
__device__ __forceinline__ void fc1_phase(const float* __restrict__ v, const float* __restrict__ w,
                                          const float* __restrict__ b, float* __restrict__ y,
                                          float* __restrict__ red) {
    int r = blockIdx.x;                 // 0..100
    int n = threadIdx.x & 127;
    int kh = threadIdx.x >> 7;          // 0/1 K-half
    float t = v[640 * B + n];
    float a0 = 0.f, a1 = 0.f, a2 = 0.f, a3 = 0.f;
    float a4 = 0.f, a5 = 0.f, a6 = 0.f, a7 = 0.f;
    if (r != 100) {
        const float* wr = w + (size_t)r * 640 + kh * 320;
        const float* vr = v + (size_t)kh * 320 * B + n;
        for (int k = 0; k < 320; k += 8) {
            float4 w0 = *(const float4*)(wr + k);
            float4 w1 = *(const float4*)(wr + k + 4);
            a0 = fmaf(w0.x, vr[(k + 0) * B], a0);
            a1 = fmaf(w0.y, vr[(k + 1) * B], a1);
            a2 = fmaf(w0.z, vr[(k + 2) * B], a2);
            a3 = fmaf(w0.w, vr[(k + 3) * B], a3);
            a4 = fmaf(w1.x, vr[(k + 4) * B], a4);
            a5 = fmaf(w1.y, vr[(k + 5) * B], a5);
            a6 = fmaf(w1.z, vr[(k + 6) * B], a6);
            a7 = fmaf(w1.w, vr[(k + 7) * B], a7);
        }
    }
    float part = ((a0 + a1) + (a2 + a3)) + ((a4 + a5) + (a6 + a7));
    if (kh) red[n] = part;
    __syncthreads();
    if (!kh) {
        float val = (r == 100) ? t : b[r] * t + part + red[n];
        y[(size_t)r * B + n] = fmaxf(val, 0.f);
    }
}

__device__ __forceinline__ void fc2_phase(const float* __restrict__ v, const float* __restrict__ w,
                                          const float* __restrict__ b, const int* __restrict__ perm,
                                          const float* __restrict__ diag, float* __restrict__ out) {
    if (threadIdx.x >= B) return;
    int jrow = blockIdx.x;
    int n = threadIdx.x;
    int r = perm[jrow];
    float d = diag[jrow];
    float t = v[100 * B + n];
    float val;
    if (r == 10) {
        val = t;
    } else {
        float a0 = 0.f, a1 = 0.f, a2 = 0.f, a3 = 0.f;
        const float* wr = w + (size_t)r * 100;
        for (int k = 0; k < 100; k += 4) {
            float4 w4 = *(const float4*)(wr + k);
            a0 = fmaf(w4.x, v[(size_t)(k + 0) * B + n], a0);
            a1 = fmaf(w4.y, v[(size_t)(k + 1) * B + n], a1);
            a2 = fmaf(w4.z, v[(size_t)(k + 2) * B + n], a2);
            a3 = fmaf(w4.w, v[(size_t)(k + 3) * B + n], a3);
        }
        val = b[r] * t + (a0 + a1) + (a2 + a3);
    }
    out[(size_t)jrow * B + n] = d * val;
}

// ---------------- the mega-kernel -------------------------------------------
__global__ __launch_bounds__(NTHR, 4) void meganet_kernel(
    WArgs A,
    const float* __restrict__ x0, const int* __restrict__ perm0, const float* __restrict__ diag0,
    const int* __restrict__ perm11, const float* __restrict__ diag11,
    const float* __restrict__ fw1, const float* __restrict__ fb1,
    const float* __restrict__ fw2, const float* __restrict__ fb2,
    f16_t* wp, float* bp, f16_t* x8a, f16_t* x8b,
    float* t0, float* t1, float* bufA, float* bufB, float* out, int* bar)
{
    __shared__ float red[128];
    // census: take a per-physical-XCD slot (stable for kernel lifetime).
    // IF-point RMWs (128-deep per XCD) are issued here and consumed only at
    // gbar(0) -> latency hides under prep_phase.
    int slot = 0;
    if (threadIdx.x == 0)
        slot = __hip_atomic_fetch_add(bar + 4640 + xcc_id(), 1, __ATOMIC_RELAXED, AGT);

    prep_phase(A, x0, perm0, diag0, wp, bp, x8a, x8b, t0);
    gbar(bar, 0, slot);
    //            KS NS SP CB F32   Hi WoL HWo  ST PD  NCG NCHK KGR  Co  Cp
    conv_layer<3, 2, 4, 2, false, 32, 5, 1024, 1, 1,  1,  3,   9,  96, 128>(
        x8a, t0, wp + A.woff[0], bp + A.boff[0], x8b, t1, nullptr);
    gbar(bar, 1, slot);
    conv_layer<3, 2, 4, 2, false, 32, 5, 1024, 1, 1, 12, 27, 108,  96, 128>(
        x8b, t1, wp + A.woff[1], bp + A.boff[1], x8a, t0, nullptr);
    gbar(bar, 2, slot);
    conv_layer<3, 1, 8, 2, false, 32, 4,  256, 2, 1, 12, 27, 108,  96, 128>(
        x8a, t0, wp + A.woff[2], bp + A.boff[2], x8b, t1, nullptr);
    gbar(bar, 3, slot);
    conv_layer<3, 2, 4, 3, false, 16, 4,  256, 1, 1, 12, 27, 108, 192, 192>(
        x8b, t1, wp + A.woff[3], bp + A.boff[3], x8a, t0, nullptr);
    gbar(bar, 4, slot);
    conv_layer<3, 2, 4, 3, false, 16, 4,  256, 1, 1, 24, 54, 216, 192, 192>(
        x8a, t0, wp + A.woff[4], bp + A.boff[4], x8b, t1, nullptr);
    gbar(bar, 5, slot);
    conv_layer<3, 1, 8, 3, false, 16, 3,   64, 2, 1, 24, 54, 216, 192, 192>(
        x8b, t1, wp + A.woff[5], bp + A.boff[5], x8a, t0, nullptr);
    gbar(bar, 6, slot);
    conv_layer<3, 1, 8, 3, false,  8, 3,   64, 1, 1, 24, 54, 216, 192, 192>(
        x8a, t0, wp + A.woff[6], bp + A.boff[6], x8b, t1, nullptr);
    gbar(bar, 7, slot);
    conv_layer<1, 1, 8, 3, false,  8, 3,   64, 1, 0, 24,  6,  24, 192, 192>(
        x8b, t1, wp + A.woff[7], bp + A.boff[7], x8a, t0, nullptr);
    gbar(bar, 8, slot);
    conv_layer<1, 1, 8, 1, true,   8, 3,   64, 1, 0, 24,  6,  24,  10,  64>(
        x8a, t0, wp + A.woff[8], bp + A.boff[8], nullptr, nullptr, bufA);
    gbar(bar, 9, slot);
    if (blockIdx.x <= 100) fc1_phase(bufA, fw1, fb1, bufB, red);
    gbar(bar, 10, slot);
    if (blockIdx.x < 11) fc2_phase(bufB, fw2, fb2, perm11, diag11, out);
}

// ---------------------------------------------------------------------------

extern "C" void kernel_launch(void* const* d_in, const int* in_sizes, int n_in,
                              void* d_out, int out_size, void* d_ws, size_t ws_size,
                              hipStream_t stream) {
    const float* x0 = (const float*)d_in[0];
    const int*   perm[12];
    const float* diag[12];
    for (int i = 0; i < 12; ++i) {
        perm[i] = (const int*)d_in[1 + 2 * i];
        diag[i] = (const float*)d_in[2 + 2 * i];
    }
    const float* wts[9];
    const float* bia[9];
    for (int j = 0; j < 9; ++j) {
        wts[j] = (const float*)d_in[25 + 2 * j];
        bia[j] = (const float*)d_in[26 + 2 * j];
    }
    const float* fw1 = (const float*)d_in[43];
    const float* fb1 = (const float*)d_in[44];
    const float* fw2 = (const float*)d_in[45];
    const float* fb2 = (const float*)d_in[46];
    float* out = (float*)d_out;

    static const int CiA[9]  = {3, 96, 96, 96, 192, 192, 192, 192, 192};
    static const int CoA[9]  = {96, 96, 96, 192, 192, 192, 192, 192, 10};
    static const int KSA[9]  = {3, 3, 3, 3, 3, 3, 3, 1, 1};
    static const int CpA[9]  = {128, 128, 128, 192, 192, 192, 192, 192, 64};
    static const int NCGA[9] = {1, 12, 12, 12, 24, 24, 24, 24, 24};
    static const int NCHK[9] = {3, 27, 27, 27, 54, 54, 54, 6, 6};

    // ----- workspace layout (same as R12, bar region grown to 20KB) -----
    char* wsb = (char*)d_ws;
    const size_t BUF_F32  = 1574912;
    const size_t X8_BYTES = (size_t)(ZPAD + 12 * 1024 * 1024) * 2;
    float* bufA = (float*)wsb;
    float* bufB = (float*)(wsb + BUF_F32);
    f16_t* x8a  = (f16_t*)(wsb + 2 * BUF_F32);
    f16_t* x8b  = (f16_t*)(wsb + 2 * BUF_F32 + X8_BYTES);
    f16_t* wpb  = (f16_t*)(wsb + 2 * BUF_F32 + 2 * X8_BYTES);
    const size_t WP_BYTES = 2888704;
    float* bpb  = (float*)(wsb + 2 * BUF_F32 + 2 * X8_BYTES + WP_BYTES);
    float* t0   = (float*)((char*)bpb + 8192);
    float* t1   = t0 + 256;
    int*   bar  = (int*)((char*)bpb + 12288);   // mids/leaf/ldone/root/census

    WArgs WA;
    int wo = 0, bo = 0;
    for (int l = 0; l < 9; ++l) {
        WA.w[l] = wts[l]; WA.b[l] = bia[l];
        WA.Ci[l] = CiA[l]; WA.Co[l] = CoA[l]; WA.KS[l] = KSA[l];
        WA.Cp[l] = CpA[l]; WA.NCG[l] = NCGA[l];
        WA.woff[l] = wo; wo += NCHK[l] * 4 * CpA[l] * 8;
        WA.boff[l] = bo; bo += CpA[l];
    }
    WA.woff[9] = wo; WA.boff[9] = bo;

    // barrier/census counters must start at 0 each replay
    hipMemsetAsync(bar, 0, 20480, stream);

    meganet_kernel<<<NBLK, NTHR, 0, stream>>>(
        WA, x0, perm[0], diag[0], perm[11], diag[11],
        fw1, fb1, fw2, fb2,
        wpb, bpb, x8a, x8b, t0, t1, bufA, bufB, out, bar);
}

// Round 5
// 379.407 us; speedup vs baseline: 1.0273x; 1.0273x over previous
//
#include <hip/hip_runtime.h>
#include <stdint.h>

// ---------------------------------------------------------------------------
// StochasticKeyNet — R14: fence-free mega-kernel via write-through shadows.
// R11-R13 post-mortem: ~16us/barrier regardless of arrival structure -> the
// cost is the release(wbl2)+acquire(inv sc1) pair: serial dirty-L2 drains,
// weights re-fetched every phase (~45MB of FETCH), 100% L2 miss restarts.
// R14: every inter-phase buffer is PHASE-UNIQUE (write-once, never before
// read this launch) and written only with agent-scope RELAXED atomic stores
// (write-through to IF, lane-coalesced).  Readers: plain cached loads; a
// never-cached address cannot be stale -> NO wbl2, NO inv, NO census.
// Barrier = vmcnt(0) drain + logical leaf/root counters + relaxed polls
// (mechanism proven in R11-R13).  Weights cached clean across all phases.
// Conv math/tiling identical to R12/R13.
// ---------------------------------------------------------------------------

#define B 128
#define ZPAD 2048   // leading zero page (elements) in each shadow buffer
#define NBLK 1024
#define NTHR 256
#define JSTRIDE ((NBLK >> 3) * 4)   // 512 wave-slots per work partition
#define LEAFN (NBLK >> 3)           // 128 blocks per logical leaf
#define AGT __HIP_MEMORY_SCOPE_AGENT

typedef _Float16 f16_t;
typedef __attribute__((ext_vector_type(8))) _Float16 f16x8;
typedef __attribute__((ext_vector_type(4))) _Float16 f16x4;
typedef __attribute__((ext_vector_type(4))) float f32x4;

struct WArgs {
    const float* w[9]; const float* b[9];
    int Ci[9], Co[9], KS[9], Cp[9], NCG[9];
    int woff[10]; int boff[10];
};

struct Bufs {
    f16_t *x8in, *S0, *S1, *S2, *S3, *S4, *S5, *S6, *S7, *wp;
    float *bp, *bufA, *bufB, *tph;
    int* bar;
};

// ---- write-through (device-coherent) stores --------------------------------
__device__ __forceinline__ void st_wt_u64(void* p, uint64_t v) {
    __hip_atomic_store((uint64_t*)p, v, __ATOMIC_RELAXED, AGT);
}
__device__ __forceinline__ void st_wt_u16(void* p, uint16_t v) {
    __hip_atomic_store((uint16_t*)p, v, __ATOMIC_RELAXED, AGT);
}
__device__ __forceinline__ void st_wt_f32(float* p, float v) {
    __hip_atomic_store(p, v, __ATOMIC_RELAXED, AGT);
}
__device__ __forceinline__ void st_wt_h(f16_t* p, f16_t v) {
    union { f16_t h; uint16_t u; } c; c.h = v;
    st_wt_u16(p, c.u);
}

// ---------------- grid barrier: counters only, no cache maintenance ---------
// bar ints: leaf (bid&7)*32 [0..255] | ldone 256+(bid&7)*32 | root 512.
// Zeroed per launch by hipMemsetAsync.  All leaf/root/poll ops are agent-
// scope (IF-point) -> correct for any block->XCD mapping.
__device__ __forceinline__ void gbar(int* bar, int ph) {
    // every wave drains its WT stores to the IF point before arriving
    asm volatile("s_waitcnt vmcnt(0)" ::: "memory");
    __syncthreads();
    if (threadIdx.x == 0) {
        int* leaf  = bar + (blockIdx.x & 7) * 32;
        int* ldone = bar + 256 + (blockIdx.x & 7) * 32;
        int* root  = bar + 512;
        int old = __hip_atomic_fetch_add(leaf, 1, __ATOMIC_RELAXED, AGT);
        if (old == (ph + 1) * LEAFN - 1) {
            __hip_atomic_fetch_add(root, 1, __ATOMIC_RELAXED, AGT);
            while (__hip_atomic_load(root, __ATOMIC_RELAXED, AGT) < (ph + 1) * 8)
                __builtin_amdgcn_s_sleep(8);
            __hip_atomic_store(ldone, ph + 1, __ATOMIC_RELAXED, AGT);
        } else {
            while (__hip_atomic_load(ldone, __ATOMIC_RELAXED, AGT) < ph + 1)
                __builtin_amdgcn_s_sleep(8);
        }
    }
    __syncthreads();
}

// ---------------- phase 0: weight pack + zero-init + decode+pack (all WT) ---
__device__ void prep_phase(const WArgs& A, const Bufs& Bf,
                           const float* __restrict__ x0, const int* __restrict__ perm0,
                           const float* __restrict__ diag0) {
    const int NT = NBLK * NTHR;
    const int gtid = blockIdx.x * NTHR + threadIdx.x;
    // zero pages (ZPAD) of input buffer + all 8 shadows (512 u64 each)
    if (gtid < 512) {
        st_wt_u64((uint64_t*)Bf.x8in + gtid, 0ull);
        st_wt_u64((uint64_t*)Bf.S0 + gtid, 0ull);
        st_wt_u64((uint64_t*)Bf.S1 + gtid, 0ull);
        st_wt_u64((uint64_t*)Bf.S2 + gtid, 0ull);
        st_wt_u64((uint64_t*)Bf.S3 + gtid, 0ull);
        st_wt_u64((uint64_t*)Bf.S4 + gtid, 0ull);
        st_wt_u64((uint64_t*)Bf.S5 + gtid, 0ull);
        st_wt_u64((uint64_t*)Bf.S6 + gtid, 0ull);
        st_wt_u64((uint64_t*)Bf.S7 + gtid, 0ull);
    }
    // zero ci%8 slots 3..7 of the l0 input region (byte-disjoint from decode)
    if (gtid < 1024 * 128) {
        int p = gtid >> 7, n = gtid & 127;
        f16_t* base = Bf.x8in + ZPAD + p * 1024 + n * 8;
        st_wt_u16(base + 3, 0);
        st_wt_u64(base + 4, 0ull);
    }
    // bias pack
    if (gtid < A.boff[9]) {
        int l = 0;
        while (gtid >= A.boff[l + 1]) ++l;
        int co = gtid - A.boff[l];
        st_wt_f32(Bf.bp + gtid, (co < A.Co[l]) ? A.b[l][co] : 0.f);
    }
    // weight pack to f16 [chunk][4][Cp][8]
    for (int idx = gtid; idx < A.woff[9]; idx += NT) {
        int l = 0;
        while (idx >= A.woff[l + 1]) ++l;
        int e = idx - A.woff[l];
        int j = e & 7;
        int t1_ = e >> 3;
        int Cp = A.Cp[l];
        int co = t1_ % Cp;
        int gg = t1_ / Cp;
        int ncg = A.NCG[l];
        int tap = gg / ncg, cg = gg - tap * ncg;
        int ks = A.KS[l];
        int kh = tap / ks, kw = tap - kh * ks;
        int ci = cg * 8 + j;
        float val = 0.f;
        if (co < A.Co[l] && tap < ks * ks && ci < A.Ci[l])
            val = A.w[l][(((size_t)co * A.Ci[l] + ci) * ks + kh) * ks + kw];
        st_wt_h(Bf.wp + idx, (f16_t)val);
    }
    // fused decode + f16 pack: v[perm[j]] = x[j]/diag[j]
    for (int idx = gtid; idx < 3073 * B; idx += NT) {
        int row = idx >> 7, n = idx & 127;
        int i = perm0[row];
        float val = x0[(size_t)row * B + n] / diag0[row];
        if (i < 3072) {
            int c = i >> 10, pp = i & 1023;
            st_wt_h(Bf.x8in + ZPAD + pp * 1024 + n * 8 + c, (f16_t)val);
        } else {
            st_wt_f32(Bf.tph + n, val);
        }
    }
}

// ---------------- one conv layer (wave-granular persistent units) -----------
// Unit j: nh (batch split) -> cog (co group) -> pixel; partition X=blockIdx&7.
template <int KS, int NS, int NSPLIT, int CB, bool F32OUT,
          int Hi, int Wo_log2, int HWo, int STRD, int PAD,
          int NCG, int NCHUNK, int KGR, int Co, int Cp>
__device__ __forceinline__ void conv_layer(
    const f16_t* __restrict__ xin, const float* __restrict__ t_in,
    const f16_t* __restrict__ wp, const float* __restrict__ bp,
    f16_t* __restrict__ xout, float* __restrict__ t_out, float* __restrict__ f32out)
{
    constexpr int PF = 2;
    constexpr int MS = 4;
    constexpr int Wi = Hi;
    constexpr int PB8 = HWo / 8;
    constexpr int UJ = NSPLIT * CB * PB8;
    constexpr int HiWi = Hi * Wi;
    constexpr int HiWi4 = 4 * HiWi;
    constexpr int NCGHW = NCG * HiWi;
    const int wv = threadIdx.x >> 6;               // 0..3
    const int lane = threadIdx.x & 63;
    const int q = lane >> 4;
    const int r = lane & 15;
    const int X = blockIdx.x & 7;

    // t-row relu (once per layer, block 0) — write-through
    if (blockIdx.x == 0 && threadIdx.x < B) {
        float tvv = fmaxf(t_in[threadIdx.x], 0.f);
        if (F32OUT) st_wt_f32(f32out + (size_t)Co * HWo * B + threadIdx.x, tvv);
        else        st_wt_f32(t_out + threadIdx.x, tvv);
    }

    for (int j = (blockIdx.x >> 3) * 4 + wv; j < UJ; j += JSTRIDE) {
        int nh = 0, j2 = j;
        if (NSPLIT > 1) { nh = j % NSPLIT; j2 = j / NSPLIT; }
        const int cog = (CB > 1) ? (j2 % CB) : 0;
        const int jp  = (CB > 1) ? (j2 / CB) : j2;
        const int p = X * PB8 + jp;
        const int co0 = cog * 64;
        const int ncol0 = nh * (NS * 16);
        const int ncol8 = ncol0 * 8;
        const int ho = p >> Wo_log2;
        const int wo = p & ((1 << Wo_log2) - 1);
        const f16_t* xdata = xin + ZPAD;

        float tv[NS];
#pragma unroll
        for (int ns = 0; ns < NS; ++ns) tv[ns] = t_in[ncol0 + ns * 16 + r];

        f32x4 acc[MS][NS];
#pragma unroll
        for (int ms = 0; ms < MS; ++ms) {
            float4 b4 = *(const float4*)(bp + co0 + ms * 16 + q * 4);
#pragma unroll
            for (int ns = 0; ns < NS; ++ns) {
                acc[ms][ns][0] = b4.x * tv[ns];
                acc[ms][ns][1] = b4.y * tv[ns];
                acc[ms][ns][2] = b4.z * tv[ns];
                acc[ms][ns][3] = b4.w * tv[ns];
            }
        }

        const int hb = ho * STRD - PAD, wb = wo * STRD - PAD;
        const int wend = wb + KS;

        int g = q, cg = q, hi = hb, wi = wb, cgHW;
        {
            while (cg >= NCG) { cg -= NCG; ++wi; if (wi == wend) { wi = wb; ++hi; } }
            cgHW = cg * HiWi;
        }

        f16x8 bf[PF][NS], af[PF][MS];

        auto advance = [&]() {
            g += 4; cg += 4; cgHW += HiWi4;
            if constexpr (NCG >= 4) {            // at most one wrap
                int c2 = cg - NCG;
                bool wrap = c2 >= 0;
                int wn = wi + 1;
                bool ww = wrap & (wn == wend);
                cg   = wrap ? c2 : cg;
                cgHW = wrap ? cgHW - NCGHW : cgHW;
                wi   = wrap ? (ww ? wb : wn) : wi;
                hi   = ww ? hi + 1 : hi;
            } else {
                while (cg >= NCG) { cg -= NCG; cgHW -= NCGHW; ++wi; if (wi == wend) { wi = wb; ++hi; } }
            }
        };
        auto loadB = [&](f16x8* bb8) {
            bool v = (g < KGR) & ((unsigned)hi < (unsigned)Hi) & ((unsigned)wi < (unsigned)Wi);
            int boff = (cgHW + hi * Wi + wi) << 10;        // *128*8 elements
            const f16_t* bb = xdata + (v ? boff : -ZPAD) + ncol8 + r * 8;
#pragma unroll
            for (int ns = 0; ns < NS; ++ns) bb8[ns] = *(const f16x8*)(bb + ns * 128);
        };
        auto loadA = [&](f16x8* a, int c) {
            int ac = c < NCHUNK ? c : NCHUNK - 1;          // clamp phantom chunks
            const f16_t* ap = wp + (((ac * 4 + q) * Cp) + co0 + r) * 8;
#pragma unroll
            for (int ms = 0; ms < MS; ++ms) a[ms] = *(const f16x8*)(ap + ms * 128);
        };
        auto domfma = [&](f16x8* a, f16x8* bb8) {
#pragma unroll
            for (int ms = 0; ms < MS; ++ms)
#pragma unroll
                for (int ns = 0; ns < NS; ++ns)
                    acc[ms][ns] = __builtin_amdgcn_mfma_f32_16x16x32_f16(a[ms], bb8[ns], acc[ms][ns], 0, 0, 0);
        };

#pragma unroll
        for (int pf = 0; pf < PF; ++pf) { loadB(bf[pf]); loadA(af[pf], pf); advance(); }
        constexpr int nck = ((NCHUNK + PF - 1) / PF) * PF;
        for (int c = 0; c < nck; c += PF) {
#pragma unroll
            for (int pf = 0; pf < PF; ++pf) {
                domfma(af[pf], bf[pf]);
                loadB(bf[pf]); loadA(af[pf], c + PF + pf); advance();
            }
        }

        if constexpr (!F32OUT) {
#pragma unroll
            for (int ms = 0; ms < MS; ++ms) {
                int cob = co0 + ms * 16 + q * 4;
                if (cob < Co) {
                    int off0 = ((cob >> 3) * HWo + p) * 1024 + (cob & 7) + ncol8 + r * 8;
#pragma unroll
                    for (int ns = 0; ns < NS; ++ns) {
                        union { f16x4 h; uint64_t u; } cu;
                        cu.h[0] = (f16_t)fmaxf(acc[ms][ns][0], 0.f);
                        cu.h[1] = (f16_t)fmaxf(acc[ms][ns][1], 0.f);
                        cu.h[2] = (f16_t)fmaxf(acc[ms][ns][2], 0.f);
                        cu.h[3] = (f16_t)fmaxf(acc[ms][ns][3], 0.f);
                        st_wt_u64(xout + ZPAD + off0 + ns * 128, cu.u);
                    }
                }
            }
        } else {
#pragma unroll
            for (int ms = 0; ms < MS; ++ms)
#pragma unroll
                for (int ns = 0; ns < NS; ++ns)
#pragma unroll
                    for (int e = 0; e < 4; ++e) {
                        int co = co0 + ms * 16 + q * 4 + e;
                        if (co < Co)
                            st_wt_f32(f32out + ((size_t)co * HWo + p) * B + ncol0 + ns * 16 + r,
                                      fmaxf(acc[ms][ns][e], 0.f));
                    }
        }
    }
}

// ---------------- FC phases -------------------------------------------------
// fc1: split-K across the two 128-thread halves, 512B LDS reduce; WT output.
__device__ __forceinline__ void fc1_phase(const float* __restrict__ v, const float* __restrict__ w,
                                          const float* __restrict__ b, float* __restrict__ y,
                                          float* __restrict__ red) {
    int r = blockIdx.x;                 // 0..100
    int n = threadIdx.x & 127;
    int kh = threadIdx.x >> 7;          // 0/1 K-half
    float t = v[640 * B + n];
    float a0 = 0.f, a1 = 0.f, a2 = 0.f, a3 = 0.f;
    float a4 = 0.f, a5 = 0.f, a6 = 0.f, a7 = 0.f;
    if (r != 100) {
        const float* wr = w + (size_t)r * 640 + kh * 320;
        const float* vr = v + (size_t)kh * 320 * B + n;
        for (int k = 0; k < 320; k += 8) {
            float4 w0 = *(const float4*)(wr + k);
            float4 w1 = *(const float4*)(wr + k + 4);
            a0 = fmaf(w0.x, vr[(k + 0) * B], a0);
            a1 = fmaf(w0.y, vr[(k + 1) * B], a1);
            a2 = fmaf(w0.z, vr[(k + 2) * B], a2);
            a3 = fmaf(w0.w, vr[(k + 3) * B], a3);
            a4 = fmaf(w1.x, vr[(k + 4) * B], a4);
            a5 = fmaf(w1.y, vr[(k + 5) * B], a5);
            a6 = fmaf(w1.z, vr[(k + 6) * B], a6);
            a7 = fmaf(w1.w, vr[(k + 7) * B], a7);
        }
    }
    float part = ((a0 + a1) + (a2 + a3)) + ((a4 + a5) + (a6 + a7));
    if (kh) red[n] = part;
    __syncthreads();
    if (!kh) {
        float val = (r == 100) ? t : b[r] * t + part + red[n];
        st_wt_f32(y + (size_t)r * B + n, fmaxf(val, 0.f));
    }
}

__device__ __forceinline__ void fc2_phase(const float* __restrict__ v, const float* __restrict__ w,
                                          const float* __restrict__ b, const int* __restrict__ perm,
                                          const float* __restrict__ diag, float* __restrict__ out) {
    if (threadIdx.x >= B) return;
    int jrow = blockIdx.x;
    int n = threadIdx.x;
    int r = perm[jrow];
    float d = diag[jrow];
    float t = v[100 * B + n];
    float val;
    if (r == 10) {
        val = t;
    } else {
        float a0 = 0.f, a1 = 0.f, a2 = 0.f, a3 = 0.f;
        const float* wr = w + (size_t)r * 100;
        for (int k = 0; k < 100; k += 4) {
            float4 w4 = *(const float4*)(wr + k);
            a0 = fmaf(w4.x, v[(size_t)(k + 0) * B + n], a0);
            a1 = fmaf(w4.y, v[(size_t)(k + 1) * B + n], a1);
            a2 = fmaf(w4.z, v[(size_t)(k + 2) * B + n], a2);
            a3 = fmaf(w4.w, v[(size_t)(k + 3) * B + n], a3);
        }
        val = b[r] * t + (a0 + a1) + (a2 + a3);
    }
    out[(size_t)jrow * B + n] = d * val;     // final: flushed by kernel-end release
}

// ---------------- the mega-kernel -------------------------------------------
__global__ __launch_bounds__(NTHR, 4) void meganet_kernel(
    WArgs A, Bufs Bf,
    const float* __restrict__ x0, const int* __restrict__ perm0, const float* __restrict__ diag0,
    const int* __restrict__ perm11, const float* __restrict__ diag11,
    const float* __restrict__ fw1, const float* __restrict__ fb1,
    const float* __restrict__ fw2, const float* __restrict__ fb2,
    float* __restrict__ out)
{
    __shared__ float red[128];
    int* bar = Bf.bar;
    float* tp = Bf.tph;

    prep_phase(A, Bf, x0, perm0, diag0);
    gbar(bar, 0);
    //            KS NS SP CB F32   Hi WoL HWo  ST PD  NCG NCHK KGR  Co  Cp
    conv_layer<3, 2, 4, 2, false, 32, 5, 1024, 1, 1,  1,  3,   9,  96, 128>(
        Bf.x8in, tp, Bf.wp + A.woff[0], Bf.bp + A.boff[0], Bf.S0, tp + 128, nullptr);
    gbar(bar, 1);
    conv_layer<3, 2, 4, 2, false, 32, 5, 1024, 1, 1, 12, 27, 108,  96, 128>(
        Bf.S0, tp + 128, Bf.wp + A.woff[1], Bf.bp + A.boff[1], Bf.S1, tp + 256, nullptr);
    gbar(bar, 2);
    conv_layer<3, 1, 8, 2, false, 32, 4,  256, 2, 1, 12, 27, 108,  96, 128>(
        Bf.S1, tp + 256, Bf.wp + A.woff[2], Bf.bp + A.boff[2], Bf.S2, tp + 384, nullptr);
    gbar(bar, 3);
    conv_layer<3, 2, 4, 3, false, 16, 4,  256, 1, 1, 12, 27, 108, 192, 192>(
        Bf.S2, tp + 384, Bf.wp + A.woff[3], Bf.bp + A.boff[3], Bf.S3, tp + 512, nullptr);
    gbar(bar, 4);
    conv_layer<3, 2, 4, 3, false, 16, 4,  256, 1, 1, 24, 54, 216, 192, 192>(
        Bf.S3, tp + 512, Bf.wp + A.woff[4], Bf.bp + A.boff[4], Bf.S4, tp + 640, nullptr);
    gbar(bar, 5);
    conv_layer<3, 1, 8, 3, false, 16, 3,   64, 2, 1, 24, 54, 216, 192, 192>(
        Bf.S4, tp + 640, Bf.wp + A.woff[5], Bf.bp + A.boff[5], Bf.S5, tp + 768, nullptr);
    gbar(bar, 6);
    conv_layer<3, 1, 8, 3, false,  8, 3,   64, 1, 1, 24, 54, 216, 192, 192>(
        Bf.S5, tp + 768, Bf.wp + A.woff[6], Bf.bp + A.boff[6], Bf.S6, tp + 896, nullptr);
    gbar(bar, 7);
    conv_layer<1, 1, 8, 3, false,  8, 3,   64, 1, 0, 24,  6,  24, 192, 192>(
        Bf.S6, tp + 896, Bf.wp + A.woff[7], Bf.bp + A.boff[7], Bf.S7, tp + 1024, nullptr);
    gbar(bar, 8);
    conv_layer<1, 1, 8, 1, true,   8, 3,   64, 1, 0, 24,  6,  24,  10,  64>(
        Bf.S7, tp + 1024, Bf.wp + A.woff[8], Bf.bp + A.boff[8], nullptr, nullptr, Bf.bufA);
    gbar(bar, 9);
    if (blockIdx.x <= 100) fc1_phase(Bf.bufA, fw1, fb1, Bf.bufB, red);
    gbar(bar, 10);
    if (blockIdx.x < 11) fc2_phase(Bf.bufB, fw2, fb2, perm11, diag11, out);
}

// ---------------------------------------------------------------------------

extern "C" void kernel_launch(void* const* d_in, const int* in_sizes, int n_in,
                              void* d_out, int out_size, void* d_ws, size_t ws_size,
                              hipStream_t stream) {
    const float* x0 = (const float*)d_in[0];
    const int*   perm[12];
    const float* diag[12];
    for (int i = 0; i < 12; ++i) {
        perm[i] = (const int*)d_in[1 + 2 * i];
        diag[i] = (const float*)d_in[2 + 2 * i];
    }
    const float* wts[9];
    const float* bia[9];
    for (int j = 0; j < 9; ++j) {
        wts[j] = (const float*)d_in[25 + 2 * j];
        bia[j] = (const float*)d_in[26 + 2 * j];
    }
    const float* fw1 = (const float*)d_in[43];
    const float* fb1 = (const float*)d_in[44];
    const float* fw2 = (const float*)d_in[45];
    const float* fb2 = (const float*)d_in[46];
    float* out = (float*)d_out;

    static const int CiA[9]  = {3, 96, 96, 96, 192, 192, 192, 192, 192};
    static const int CoA[9]  = {96, 96, 96, 192, 192, 192, 192, 192, 10};
    static const int KSA[9]  = {3, 3, 3, 3, 3, 3, 3, 1, 1};
    static const int CpA[9]  = {128, 128, 128, 192, 192, 192, 192, 192, 64};
    static const int NCGA[9] = {1, 12, 12, 12, 24, 24, 24, 24, 24};
    static const int NCHK[9] = {3, 27, 27, 27, 54, 54, 54, 6, 6};

    // ----- workspace layout: phase-unique shadows (sizes in bytes, 4K-align)
    char* p = (char*)d_ws;
    auto take = [&](size_t bytes) { char* q = p; p += (bytes + 4095) & ~(size_t)4095; return q; };
    Bufs Bf;
    Bf.x8in = (f16_t*)take((ZPAD + 1024 * 1024) * 2);            // l0 input (1 cg)
    Bf.S0   = (f16_t*)take((ZPAD + 12 * 1024 * 1024) * 2);       // 96ch 32x32
    Bf.S1   = (f16_t*)take((ZPAD + 12 * 1024 * 1024) * 2);
    Bf.S2   = (f16_t*)take((ZPAD + 3 * 1024 * 1024) * 2);        // 96ch 16x16
    Bf.S3   = (f16_t*)take((ZPAD + 6 * 1024 * 1024) * 2);        // 192ch 16x16
    Bf.S4   = (f16_t*)take((ZPAD + 6 * 1024 * 1024) * 2);
    Bf.S5   = (f16_t*)take((ZPAD + 1536 * 1024) * 2);            // 192ch 8x8
    Bf.S6   = (f16_t*)take((ZPAD + 1536 * 1024) * 2);
    Bf.S7   = (f16_t*)take((ZPAD + 1536 * 1024) * 2);
    Bf.wp   = (f16_t*)take(2888704);
    Bf.bp   = (float*)take(8192);
    Bf.bufA = (float*)take(641 * 128 * 4);
    Bf.bufB = (float*)take(101 * 128 * 4);
    Bf.tph  = (float*)take(10 * 128 * 4);
    Bf.bar  = (int*)  take(4096);

    WArgs WA;
    int wo = 0, bo = 0;
    for (int l = 0; l < 9; ++l) {
        WA.w[l] = wts[l]; WA.b[l] = bia[l];
        WA.Ci[l] = CiA[l]; WA.Co[l] = CoA[l]; WA.KS[l] = KSA[l];
        WA.Cp[l] = CpA[l]; WA.NCG[l] = NCGA[l];
        WA.woff[l] = wo; wo += NCHK[l] * 4 * CpA[l] * 8;
        WA.boff[l] = bo; bo += CpA[l];
    }
    WA.woff[9] = wo; WA.boff[9] = bo;

    // barrier counters must start at 0 each replay
    hipMemsetAsync(Bf.bar, 0, 4096, stream);

    meganet_kernel<<<NBLK, NTHR, 0, stream>>>(
        WA, Bf, x0, perm[0], diag[0], perm[11], diag[11],
        fw1, fb1, fw2, fb2, out);
}